// Round 1
// baseline (485.565 us; speedup 1.0000x reference)
//
#include <hip/hip_runtime.h>

// Correlation cost volume, specialized: B=16, C=256, H=W=96, k=1, d=4, s1=s2=1.
// out[b, (dy+4)*9+(dx+4), y, x] = (1/256) * sum_c x1[b,c,y,x] * x2[b,c,y+dy,x+dx]
// (x2 zero-padded by 4). Thread owns (8-pixel x-strip, one dy, all 9 dx) -> 72 accs.
// Block = 4 rows x 9 dy x 12 strips = 432 threads; grid = 24 row-tiles x 16 batch.

namespace {
constexpr int Bsz = 16, Cch = 256, Hh = 96, Ww = 96;
constexpr int Dd = 4, NDisp = 9;            // 2*d+1
constexpr int TH = 4;                       // output rows per block
constexpr int PX = 8;                       // pixels per thread (x)
constexpr int NSTRIP = Ww / PX;             // 12
constexpr int CC = 4;                       // channels per LDS stage
constexpr int X2ROWS = TH + 2 * Dd;         // 12
constexpr int X2P = 105;                    // odd pitch -> <=3-way LDS bank conflicts
constexpr int NT = TH * NDisp * NSTRIP;     // 432 threads
constexpr int HW = Hh * Ww;                 // 9216
constexpr int X1_LDS = CC * TH * Ww;        // 1536 dwords
constexpr int X2_LDS = CC * X2ROWS * X2P;   // 5040 dwords
constexpr int X1_F4 = X1_LDS / 4;           // 384 float4 staging items
constexpr int X2_GROUPS = 26;               // 104 padded cols / 4
constexpr int X2_F4 = CC * X2ROWS * X2_GROUPS;  // 1248 items
constexpr int N_ITEMS = X1_F4 + X2_F4;      // 1632 -> <=4 per thread
}

__global__ __launch_bounds__(NT, 2)
void corr81(const float* __restrict__ x1, const float* __restrict__ x2,
            float* __restrict__ out) {
  __shared__ float lds[X1_LDS + X2_LDS + 4];  // +4 = dummy slot for invalid items

  const int t = threadIdx.x;
  const int y0 = blockIdx.x * TH;
  const int b  = blockIdx.y;

  const int r   = t / (NDisp * NSTRIP);   // 0..3  output row within tile
  const int rem = t % (NDisp * NSTRIP);
  const int dyi = rem / NSTRIP;           // 0..8  (dy+4)
  const int s   = rem % NSTRIP;           // 0..11 strip
  const int x0  = s * PX;

  const float* __restrict__ x1b = x1 + (size_t)b * Cch * HW;
  const float* __restrict__ x2b = x2 + (size_t)b * Cch * HW;

  // ---- precompute staging descriptors (constant 4 slots, mask invalid) ----
  const float* gp[4];
  int  loff[4];
  bool zero[4];
#pragma unroll
  for (int j = 0; j < 4; ++j) {
    int i = t + j * NT;
    if (i >= N_ITEMS) {                     // pad slot: write to dummy LDS tail
      gp[j] = x1b; loff[j] = X1_LDS + X2_LDS; zero[j] = true;
    } else if (i < X1_F4) {
      int c = i / (TH * Ww / 4);            // 96 f4 per channel (4 contiguous rows)
      int q = i % (TH * Ww / 4);
      gp[j]   = x1b + c * HW + y0 * Ww + q * 4;
      loff[j] = c * (TH * Ww) + q * 4;      // pitch 96, f4-aligned
      zero[j] = false;
    } else {
      int m  = i - X1_F4;
      int c  = m / (X2ROWS * X2_GROUPS);
      int m2 = m % (X2ROWS * X2_GROUPS);
      int ry = m2 / X2_GROUPS;              // 0..11 padded row
      int g  = m2 % X2_GROUPS;              // col group: padded cols [4g,4g+3]
      int gy = y0 + ry - Dd;
      bool z = (gy < 0) | (gy >= Hh) | (g == 0) | (g == X2_GROUPS - 1);
      gp[j]   = z ? x2b : (x2b + c * HW + gy * Ww + (g - 1) * 4);
      loff[j] = X1_LDS + c * (X2ROWS * X2P) + ry * X2P + g * 4;  // 4B-aligned only
      zero[j] = z;
    }
  }

  float acc[NDisp][PX];
#pragma unroll
  for (int i = 0; i < NDisp; ++i)
#pragma unroll
    for (int j = 0; j < PX; ++j) acc[i][j] = 0.f;

  // ---- prefetch stage 0 into registers ----
  float4 v[4];
#pragma unroll
  for (int j = 0; j < 4; ++j)
    v[j] = zero[j] ? make_float4(0.f, 0.f, 0.f, 0.f) : *(const float4*)gp[j];

  for (int c0 = 0; c0 < Cch; c0 += CC) {
    __syncthreads();                        // previous compute done with LDS
    // registers -> LDS (x1 pitch 96 stays f4; x2 pitch 105 needs scalar stores)
#pragma unroll
    for (int j = 0; j < 4; ++j) {
      int o = loff[j];
      if (o < X1_LDS) {
        *(float4*)(lds + o) = v[j];
      } else {
        lds[o] = v[j].x; lds[o + 1] = v[j].y; lds[o + 2] = v[j].z; lds[o + 3] = v[j].w;
      }
    }
    __syncthreads();
    // issue next stage's global loads before compute -> latency overlap
    if (c0 + CC < Cch) {
#pragma unroll
      for (int j = 0; j < 4; ++j) {
        gp[j] += CC * HW;
        v[j] = zero[j] ? make_float4(0.f, 0.f, 0.f, 0.f) : *(const float4*)gp[j];
      }
    }
    // ---- compute: per channel 8 x1 + 16 x2 LDS floats, 72 FMAs ----
#pragma unroll
    for (int cc = 0; cc < CC; ++cc) {
      const float* ap = lds + cc * (TH * Ww) + r * Ww + x0;
      float a[PX];
      *(float4*)(a)     = *(const float4*)(ap);
      *(float4*)(a + 4) = *(const float4*)(ap + 4);
      const float* bp = lds + X1_LDS + cc * (X2ROWS * X2P) + (r + dyi) * X2P + x0;
      float bb[PX + 2 * Dd];
#pragma unroll
      for (int q = 0; q < PX + 2 * Dd; ++q) bb[q] = bp[q];  // padded cols x0..x0+15
#pragma unroll
      for (int dx = 0; dx < NDisp; ++dx)
#pragma unroll
        for (int px = 0; px < PX; ++px)
          acc[dx][px] += a[px] * bb[px + dx];
    }
  }

  // ---- epilogue: 9 channels x 8 contiguous pixels per thread ----
  const float nrm = 1.0f / (float)Cch;
  float* ob = out + ((size_t)b * (NDisp * NDisp) + (size_t)dyi * NDisp) * HW
                  + (size_t)(y0 + r) * Ww + x0;
#pragma unroll
  for (int dx = 0; dx < NDisp; ++dx) {
    float4 w0, w1;
    w0.x = acc[dx][0] * nrm; w0.y = acc[dx][1] * nrm;
    w0.z = acc[dx][2] * nrm; w0.w = acc[dx][3] * nrm;
    w1.x = acc[dx][4] * nrm; w1.y = acc[dx][5] * nrm;
    w1.z = acc[dx][6] * nrm; w1.w = acc[dx][7] * nrm;
    *(float4*)(ob + (size_t)dx * HW)     = w0;
    *(float4*)(ob + (size_t)dx * HW + 4) = w1;
  }
}

extern "C" void kernel_launch(void* const* d_in, const int* in_sizes, int n_in,
                              void* d_out, int out_size, void* d_ws, size_t ws_size,
                              hipStream_t stream) {
  const float* x1 = (const float*)d_in[0];
  const float* x2 = (const float*)d_in[1];
  float* out = (float*)d_out;
  dim3 grid(Hh / TH, Bsz);   // 24 row-tiles x 16 batches = 384 blocks
  dim3 block(NT);            // 432 threads
  hipLaunchKernelGGL(corr81, grid, block, 0, stream, x1, x2, out);
}